// Round 3
// baseline (287.743 us; speedup 1.0000x reference)
//
#include <hip/hip_runtime.h>
#include <hip/hip_bf16.h>

// Problem constants (from reference)
#define BB 2
#define TT 1024
#define CC 2048
#define NCH 8
#define KLAT 32
#define NKV 4
#define NREP 4
#define DD 128
#define MROWS (BB*TT)          // 2048
#define CSROWS (BB*NCH*KLAT)   // 512
#define NBUCKET 16             // B * NCH
#define TTILE 8                // tokens per attention tile
#define MAXTILES (MROWS/TTILE + NBUCKET)   // 272

typedef unsigned short u16;
typedef __attribute__((ext_vector_type(8))) short bf16x8;   // MFMA A/B frag (4 VGPRs)
typedef __attribute__((ext_vector_type(4))) float f32x4;    // MFMA C/D frag
typedef __attribute__((ext_vector_type(8))) u16 u16x8;

__device__ __forceinline__ u16 f2bf(float f) {
    unsigned int u = __builtin_bit_cast(unsigned int, f);
    u = (u + 0x7FFFu + ((u >> 16) & 1u)) >> 16;   // RNE; inputs finite
    return (u16)u;
}

// async global->LDS, 16B per lane. LDS dest = wave-uniform base + lane*16.
__device__ __forceinline__ void glds16(const u16* g, u16* l) {
    __builtin_amdgcn_global_load_lds(
        (const __attribute__((address_space(1))) void*)g,
        (__attribute__((address_space(3))) void*)l, 16, 0, 0);
}

// ---------------- elementwise fp32 -> bf16 ----------------
__global__ void __launch_bounds__(256)
cvt_bf16_kernel(const float* __restrict__ in, u16* __restrict__ out, int n) {
    int i = (blockIdx.x * 256 + threadIdx.x) * 8;
    if (i >= n) return;
    float4 a = *(const float4*)(in + i);
    float4 b = *(const float4*)(in + i + 4);
    u16x8 o;
    o[0]=f2bf(a.x); o[1]=f2bf(a.y); o[2]=f2bf(a.z); o[3]=f2bf(a.w);
    o[4]=f2bf(b.x); o[5]=f2bf(b.y); o[6]=f2bf(b.z); o[7]=f2bf(b.w);
    *(u16x8*)(out + i) = o;
}

// ---------------- transpose + convert: in (R x C) fp32 -> out (C x R) bf16 ----------------
__global__ void __launch_bounds__(256)
tcvt_kernel(const float* __restrict__ in, u16* __restrict__ out, int R, int C) {
    __shared__ u16 tile[64][65];
    const int c0 = blockIdx.x * 64;
    const int r0 = blockIdx.y * 64;
    const int tid = threadIdx.x;
    const int tx = tid & 15;
    const int ty = tid >> 4;
#pragma unroll
    for (int p = 0; p < 4; ++p) {
        int r = p * 16 + ty;
        float4 v = *(const float4*)(in + (size_t)(r0 + r) * C + c0 + tx * 4);
        tile[tx*4+0][r] = f2bf(v.x);
        tile[tx*4+1][r] = f2bf(v.y);
        tile[tx*4+2][r] = f2bf(v.z);
        tile[tx*4+3][r] = f2bf(v.w);
    }
    __syncthreads();
    const int oc = tid >> 2;
    const int op = tid & 3;
    u16* dst = out + (size_t)(c0 + oc) * R + r0 + op * 16;
    u16x8 v0, v1;
#pragma unroll
    for (int j = 0; j < 8; ++j) { v0[j] = tile[oc][op*16 + j]; v1[j] = tile[oc][op*16 + 8 + j]; }
    *(u16x8*)dst = v0;
    *(u16x8*)(dst + 8) = v1;
}

// ---------------- bf16 GEMM with global_load_lds staging (m97 2-barrier) ----------------
// A: M x K bf16 row-major; Bt: N x K bf16 row-major; C: M x N.
// OUT: 3 = atomic f32 (split-K), 4 = atomic f32 * tanh(gate) (split-K)
template<int BM, int BN, int OUT>
__global__ void __launch_bounds__(256)
gemm_glds_kernel(const u16* __restrict__ A, const u16* __restrict__ Bt,
                 void* __restrict__ Cp, int M, int N, int K, int kChunk,
                 const float* __restrict__ gate)
{
    constexpr int BK = 32;
    __shared__ u16 As[BM * BK];
    __shared__ u16 Bs[BN * BK];
    const int tid  = threadIdx.x;
    const int wave = tid >> 6;
    const int lane = tid & 63;
    const int m0   = blockIdx.x * BM;
    const int n0   = blockIdx.y * BN;
    const int kbeg = blockIdx.z * kChunk;
    constexpr int WM = BM / 2, WN = BN / 2;
    constexpr int MI = WM / 16, NI = WN / 16;
    const int wm = (wave & 1) * WM;
    const int wn = (wave >> 1) * WN;
    const int ml = lane & 15;
    const int quad = lane >> 4;

    f32x4 acc[MI][NI];
#pragma unroll
    for (int i = 0; i < MI; ++i)
#pragma unroll
        for (int j = 0; j < NI; ++j) acc[i][j] = (f32x4){0.f, 0.f, 0.f, 0.f};

    constexpr int RA = (BM * BK) / 2048;   // staging rounds (2048 u16 per round)
    constexpr int RB = (BN * BK) / 2048;
    const u16* aptr = A  + (size_t)(m0 + (tid >> 2)) * K + kbeg + (tid & 3) * 8;
    const u16* bptr = Bt + (size_t)(n0 + (tid >> 2)) * K + kbeg + (tid & 3) * 8;
    u16* As_w = As + wave * 512;   // wave-uniform LDS base (1024 B per wave)
    u16* Bs_w = Bs + wave * 512;

    for (int k0 = 0; k0 < kChunk; k0 += BK) {
        __syncthreads();   // previous tile's frags consumed
#pragma unroll
        for (int p = 0; p < RA; ++p) glds16(aptr + (size_t)p * 64 * K + k0, As_w + p * 2048);
#pragma unroll
        for (int p = 0; p < RB; ++p) glds16(bptr + (size_t)p * 64 * K + k0, Bs_w + p * 2048);
        __syncthreads();   // drains vmcnt -> LDS data visible
        bf16x8 afr[MI], bfr[NI];
#pragma unroll
        for (int i = 0; i < MI; ++i)
            afr[i] = *(const bf16x8*)&As[(wm + i * 16 + ml) * BK + quad * 8];
#pragma unroll
        for (int j = 0; j < NI; ++j)
            bfr[j] = *(const bf16x8*)&Bs[(wn + j * 16 + ml) * BK + quad * 8];
#pragma unroll
        for (int i = 0; i < MI; ++i)
#pragma unroll
            for (int j = 0; j < NI; ++j)
                acc[i][j] = __builtin_amdgcn_mfma_f32_16x16x32_bf16(afr[i], bfr[j], acc[i][j], 0, 0, 0);
    }

    float scl = 1.0f;
    if (OUT == 4) scl = tanhf(gate[0]);
    // C/D layout (m89/m91): col = lane&15, row = quad*4 + reg
#pragma unroll
    for (int i = 0; i < MI; ++i)
#pragma unroll
        for (int j = 0; j < NI; ++j)
#pragma unroll
            for (int rr = 0; rr < 4; ++rr) {
                int gr = m0 + wm + i * 16 + quad * 4 + rr;
                int gc = n0 + wn + j * 16 + ml;
                float val = acc[i][j][rr];
                if (OUT == 4) val *= scl;
                atomicAdd((float*)Cp + (size_t)gr * N + gc, val);
            }
}

// ---------------- counting sort of tokens by (b, channel) ----------------
__global__ void __launch_bounds__(256)
sort_kernel(const int* __restrict__ cmask, int* __restrict__ sorted,
            int4* __restrict__ tiles, int* __restrict__ ntiles)
{
    __shared__ int cnt[NBUCKET], cur[NBUCKET];
    int t = threadIdx.x;
    if (t < NBUCKET) cnt[t] = 0;
    __syncthreads();
    for (int i = t; i < MROWS; i += 256) {
        int bkt = ((i >> 10) << 3) | cmask[i];
        atomicAdd(&cnt[bkt], 1);
    }
    __syncthreads();
    if (t == 0) {
        int off = 0, nt = 0;
        for (int b2 = 0; b2 < NBUCKET; ++b2) {
            cur[b2] = off;
            for (int o = 0; o < cnt[b2]; o += TTILE)
                tiles[nt++] = make_int4(b2, off + o, min(TTILE, cnt[b2] - o), 0);
            off += cnt[b2];
        }
        *ntiles = nt;
    }
    __syncthreads();
    for (int i = t; i < MROWS; i += 256) {
        int bkt = ((i >> 10) << 3) | cmask[i];
        int pos = atomicAdd(&cur[bkt], 1);
        sorted[pos] = i;
    }
}

// ---------------- kv fp32 -> kb bf16 (as-is) + vt bf16 (transposed) ----------------
// kvf: (512 rows = (b,n,lat), 1024 cols = [k: g*128+d | v: g*128+d]) fp32
// kb:  (512 rows, 512 cols) bf16;  vt: ((b,n,g), d, lat) bf16
__global__ void __launch_bounds__(256)
kvcvt_kernel(const float* __restrict__ kvf, u16* __restrict__ kb, u16* __restrict__ vt)
{
    const int bn = blockIdx.x >> 2;
    const int g  = blockIdx.x & 3;
    const int t  = threadIdx.x;
#pragma unroll
    for (int i = 0; i < 16; ++i) {
        int flat = i * 256 + t;           // 0..4095
        int lat = flat >> 7, d = flat & 127;
        kb[(size_t)(bn * 32 + lat) * 512 + g * 128 + d] =
            f2bf(kvf[(size_t)(bn * 32 + lat) * 1024 + g * 128 + d]);
        int d2 = flat >> 5, lat2 = flat & 31;
        vt[((size_t)bn * 4 + g) * 4096 + d2 * 32 + lat2] =
            f2bf(kvf[(size_t)(bn * 32 + lat2) * 1024 + 512 + g * 128 + d2]);
    }
}

// ---------------- MFMA attention: one (tile of 8 same-channel tokens, group g) per wave ----------------
// qf: (2048, 2048) fp32, col = g*512 + r*128 + d (converted to bf16 frags on load)
// kb: (512 rows=(b,n,lat), 512 cols=g*128+d) bf16
// vt: ((b,n,g), d=128, lat=32) bf16
// yb: (2048, 2048) bf16 (same col layout as qf)
#define KSTR 136   // k_lds row stride (u16)
#define VSTR 40    // v_lds / p_lds row stride (u16)
__global__ void __launch_bounds__(64)
attn_mfma_kernel(const float* __restrict__ qf, const u16* __restrict__ kb,
                 const u16* __restrict__ vt, const int* __restrict__ sorted,
                 const int4* __restrict__ tiles, const int* __restrict__ ntiles,
                 u16* __restrict__ yb)
{
    const int tile = blockIdx.x;
    if (tile >= *ntiles) return;
    const int g = blockIdx.y;
    const int4 td = tiles[tile];
    const int bucket = td.x, start = td.y, cnt = td.z;
    const int lane = threadIdx.x;
    const int ml = lane & 15, quad = lane >> 4;

    __shared__ u16 k_lds[32 * KSTR];    // K_g: (lat, d)
    __shared__ u16 v_lds[128 * VSTR];   // V_g^T: (d, lat)
    __shared__ u16 p_lds[32 * VSTR];    // P: (m, lat)
    __shared__ int tok_s[TTILE];

    if (lane < TTILE) tok_s[lane] = (lane < cnt) ? sorted[start + lane] : -1;

    // stage K_g (32x128) and V_g^T (128x32)
    {
        const u16* ksrc = kb + (size_t)bucket * 32 * 512 + g * 128;
        const u16* vsrc = vt + ((size_t)bucket * 4 + g) * 4096;
#pragma unroll
        for (int rr = 0; rr < 8; ++rr) {
            int f = rr * 64 + lane;
            int krow = f >> 4, kc = (f & 15) * 8;
            *(u16x8*)&k_lds[krow * KSTR + kc] = *(const u16x8*)(ksrc + (size_t)krow * 512 + kc);
            int vd = f >> 2, vc = (f & 3) * 8;
            *(u16x8*)&v_lds[vd * VSTR + vc] = *(const u16x8*)(vsrc + (size_t)f * 8);
        }
    }
    __syncthreads();

    // scores: D[m][lat]; m-tile i: tok = tok_s[m&7], r = i*2 + (m>>3); K=128 in 4 steps
    f32x4 sc[2][2];
#pragma unroll
    for (int i = 0; i < 2; ++i)
#pragma unroll
        for (int j = 0; j < 2; ++j) sc[i][j] = (f32x4){0.f, 0.f, 0.f, 0.f};
    const int tokA = tok_s[ml & 7];
    const float* qrow = qf + (size_t)(tokA >= 0 ? tokA : 0) * 2048 + g * 512 + (ml >> 3) * 128;
#pragma unroll
    for (int s = 0; s < 4; ++s) {
        bf16x8 bfr0 = *(const bf16x8*)&k_lds[ml * KSTR + s * 32 + quad * 8];
        bf16x8 bfr1 = *(const bf16x8*)&k_lds[(16 + ml) * KSTR + s * 32 + quad * 8];
#pragma unroll
        for (int i = 0; i < 2; ++i) {
            const float* qp = qrow + i * 256 + s * 32 + quad * 8;
            float4 qa = *(const float4*)qp;
            float4 qc = *(const float4*)(qp + 4);
            bf16x8 afr;
            afr[0]=f2bf(qa.x); afr[1]=f2bf(qa.y); afr[2]=f2bf(qa.z); afr[3]=f2bf(qa.w);
            afr[4]=f2bf(qc.x); afr[5]=f2bf(qc.y); afr[6]=f2bf(qc.z); afr[7]=f2bf(qc.w);
            sc[i][0] = __builtin_amdgcn_mfma_f32_16x16x32_bf16(afr, bfr0, sc[i][0], 0, 0, 0);
            sc[i][1] = __builtin_amdgcn_mfma_f32_16x16x32_bf16(afr, bfr1, sc[i][1], 0, 0, 0);
        }
    }

    // per-row softmax over 32 latents
    const float scale = 0.088388347648318447f;   // 1/sqrt(128)
#pragma unroll
    for (int i = 0; i < 2; ++i)
#pragma unroll
        for (int reg = 0; reg < 4; ++reg) {
            float s0 = sc[i][0][reg] * scale;
            float s1 = sc[i][1][reg] * scale;
            float mx = fmaxf(s0, s1);
            mx = fmaxf(mx, __shfl_xor(mx, 1));
            mx = fmaxf(mx, __shfl_xor(mx, 2));
            mx = fmaxf(mx, __shfl_xor(mx, 4));
            mx = fmaxf(mx, __shfl_xor(mx, 8));
            float e0 = __expf(s0 - mx), e1 = __expf(s1 - mx);
            float sm = e0 + e1;
            sm += __shfl_xor(sm, 1);
            sm += __shfl_xor(sm, 2);
            sm += __shfl_xor(sm, 4);
            sm += __shfl_xor(sm, 8);
            float inv = 1.0f / sm;
            int prow = i * 16 + quad * 4 + reg;
            p_lds[prow * VSTR + ml]      = f2bf(e0 * inv);
            p_lds[prow * VSTR + 16 + ml] = f2bf(e1 * inv);
        }
    __syncthreads();

    // PV: y[m][d] = sum_lat P[m][lat] * V[lat][d]
    bf16x8 pfr[2], vfr[8];
    pfr[0] = *(const bf16x8*)&p_lds[ml * VSTR + quad * 8];
    pfr[1] = *(const bf16x8*)&p_lds[(16 + ml) * VSTR + quad * 8];
#pragma unroll
    for (int j = 0; j < 8; ++j)
        vfr[j] = *(const bf16x8*)&v_lds[(j * 16 + ml) * VSTR + quad * 8];
#pragma unroll
    for (int i = 0; i < 2; ++i)
#pragma unroll
        for (int j = 0; j < 8; ++j) {
            f32x4 o = (f32x4){0.f, 0.f, 0.f, 0.f};
            o = __builtin_amdgcn_mfma_f32_16x16x32_bf16(pfr[i], vfr[j], o, 0, 0, 0);
#pragma unroll
            for (int reg = 0; reg < 4; ++reg) {
                int m = quad * 4 + reg;
                int tok = tok_s[m & 7];
                if (tok >= 0) {
                    int r = i * 2 + (m >> 3);
                    yb[(size_t)tok * 2048 + g * 512 + r * 128 + j * 16 + ml] = f2bf(o[reg]);
                }
            }
        }
}

extern "C" void kernel_launch(void* const* d_in, const int* in_sizes, int n_in,
                              void* d_out, int out_size, void* d_ws, size_t ws_size,
                              hipStream_t stream) {
    const float* x    = (const float*)d_in[0];
    const float* cs   = (const float*)d_in[1];
    const int*   cm   = (const int*)d_in[2];
    const float* Wq   = (const float*)d_in[3];
    const float* Wk   = (const float*)d_in[4];
    const float* Wv   = (const float*)d_in[5];
    const float* Wo   = (const float*)d_in[6];
    const float* gate = (const float*)d_in[7];
    float* out = (float*)d_out;

    // workspace layout (16B aligned). csb/wkvt/kvf are fully consumed
    // (by kvcvt) before the q-GEMM writes qf, so they alias qf's region.
    char* w = (char*)d_ws;
    u16* xb   = (u16*)w;  w += (size_t)MROWS * CC * 2;        // 8.4 MB
    u16* wqt  = (u16*)w;  w += (size_t)CC * CC * 2;           // 8.4 MB
    u16* wot  = (u16*)w;  w += (size_t)CC * CC * 2;           // 8.4 MB
    float* qf = (float*)w;                                    // 16.8 MB region
    u16*   csb  = (u16*)w;                                    //   alias +0    (2.1 MB)
    u16*   wkvt = (u16*)(w + (size_t)CSROWS * CC * 2);        //   alias +2.1  (4.2 MB)
    float* kvf  = (float*)(w + (size_t)CSROWS * CC * 2 + (size_t)1024 * CC * 2); // +6.3 (2.1 MB)
    w += (size_t)MROWS * CC * 4;
    u16* yb   = (u16*)w;  w += (size_t)MROWS * CC * 2;        // 8.4 MB
    u16* kb   = (u16*)w;  w += (size_t)CSROWS * 512 * 2;      // 0.5 MB
    u16* vt   = (u16*)w;  w += (size_t)64 * 128 * 32 * 2;     // 0.5 MB
    int* sorted = (int*)w; w += (size_t)MROWS * 4;
    int4* tiles = (int4*)w; w += (size_t)MAXTILES * 16;
    int* ntiles = (int*)w;  w += 16;

    // ---- KV pipeline first (uses the alias region) ----
    hipMemsetAsync(kvf, 0, (size_t)CSROWS * 1024 * 4, stream);
    sort_kernel<<<1, 256, 0, stream>>>(cm, sorted, tiles, ntiles);
    cvt_bf16_kernel<<<(CSROWS * CC) / 2048, 256, 0, stream>>>(cs, csb, CSROWS * CC);
    tcvt_kernel<<<dim3(512 / 64, CC / 64), 256, 0, stream>>>(Wk, wkvt, CC, 512);
    tcvt_kernel<<<dim3(512 / 64, CC / 64), 256, 0, stream>>>(Wv, wkvt + (size_t)512 * CC, CC, 512);
    // kv = cs @ [Wk|Wv], 128x128 tile, split-K=8 (grid 256)
    gemm_glds_kernel<128, 128, 3><<<dim3(CSROWS / 128, 1024 / 128, 8), 256, 0, stream>>>(
        csb, wkvt, kvf, CSROWS, 1024, CC, CC / 8, nullptr);
    kvcvt_kernel<<<64, 256, 0, stream>>>(kvf, kb, vt);

    // ---- Q pipeline (alias region now free -> qf) ----
    cvt_bf16_kernel<<<(MROWS * CC) / 2048, 256, 0, stream>>>(x, xb, MROWS * CC);
    tcvt_kernel<<<dim3(CC / 64, CC / 64), 256, 0, stream>>>(Wq, wqt, CC, CC);
    hipMemsetAsync(qf, 0, (size_t)MROWS * CC * 4, stream);
    // q = x @ Wq, 128x128 tile, split-K=2 (grid 512, 2 blocks/CU)
    gemm_glds_kernel<128, 128, 3><<<dim3(MROWS / 128, CC / 128, 2), 256, 0, stream>>>(
        xb, wqt, qf, MROWS, CC, CC, CC / 2, nullptr);

    // ---- attention + output ----
    tcvt_kernel<<<dim3(CC / 64, CC / 64), 256, 0, stream>>>(Wo, wot, CC, CC);
    attn_mfma_kernel<<<dim3(MAXTILES, 4), 64, 0, stream>>>(qf, kb, vt, sorted, tiles, ntiles, yb);
    hipMemsetAsync(out, 0, (size_t)MROWS * CC * 4, stream);
    // out = (y @ Wo) * tanh(gate), 128x128 tile, split-K=2
    gemm_glds_kernel<128, 128, 4><<<dim3(MROWS / 128, CC / 128, 2), 256, 0, stream>>>(
        yb, wot, out, MROWS, CC, CC, CC / 2, gate);
}

// Round 4
// 238.363 us; speedup vs baseline: 1.2072x; 1.2072x over previous
//
#include <hip/hip_runtime.h>
#include <hip/hip_bf16.h>

// Problem constants (from reference)
#define BB 2
#define TT 1024
#define CC 2048
#define NCH 8
#define KLAT 32
#define NKV 4
#define NREP 4
#define DD 128
#define MROWS (BB*TT)          // 2048
#define CSROWS (BB*NCH*KLAT)   // 512
#define NBUCKET 16             // B * NCH
#define TTILE 8                // tokens per attention tile
#define MAXTILES (MROWS/TTILE + NBUCKET)   // 272

typedef unsigned short u16;
typedef __attribute__((ext_vector_type(8))) short bf16x8;   // MFMA A/B frag (4 VGPRs)
typedef __attribute__((ext_vector_type(4))) float f32x4;    // MFMA C/D frag
typedef __attribute__((ext_vector_type(8))) u16 u16x8;

__device__ __forceinline__ u16 f2bf(float f) {
    unsigned int u = __builtin_bit_cast(unsigned int, f);
    u = (u + 0x7FFFu + ((u >> 16) & 1u)) >> 16;   // RNE; inputs finite
    return (u16)u;
}

// async global->LDS, 16B per lane. LDS dest = wave-uniform base + lane*16.
__device__ __forceinline__ void glds16(const u16* g, u16* l) {
    __builtin_amdgcn_global_load_lds(
        (const __attribute__((address_space(1))) void*)g,
        (__attribute__((address_space(3))) void*)l, 16, 0, 0);
}

// ---------------- elementwise fp32 -> bf16 ----------------
__global__ void __launch_bounds__(256)
cvt_bf16_kernel(const float* __restrict__ in, u16* __restrict__ out, int n) {
    int i = (blockIdx.x * 256 + threadIdx.x) * 8;
    if (i >= n) return;
    float4 a = *(const float4*)(in + i);
    float4 b = *(const float4*)(in + i + 4);
    u16x8 o;
    o[0]=f2bf(a.x); o[1]=f2bf(a.y); o[2]=f2bf(a.z); o[3]=f2bf(a.w);
    o[4]=f2bf(b.x); o[5]=f2bf(b.y); o[6]=f2bf(b.z); o[7]=f2bf(b.w);
    *(u16x8*)(out + i) = o;
}

// ---------------- transpose + convert: in (R x C) fp32 -> out (C x R) bf16 ----------------
__global__ void __launch_bounds__(256)
tcvt_kernel(const float* __restrict__ in, u16* __restrict__ out, int R, int C) {
    __shared__ u16 tile[64][65];
    const int c0 = blockIdx.x * 64;
    const int r0 = blockIdx.y * 64;
    const int tid = threadIdx.x;
    const int tx = tid & 15;
    const int ty = tid >> 4;
#pragma unroll
    for (int p = 0; p < 4; ++p) {
        int r = p * 16 + ty;
        float4 v = *(const float4*)(in + (size_t)(r0 + r) * C + c0 + tx * 4);
        tile[tx*4+0][r] = f2bf(v.x);
        tile[tx*4+1][r] = f2bf(v.y);
        tile[tx*4+2][r] = f2bf(v.z);
        tile[tx*4+3][r] = f2bf(v.w);
    }
    __syncthreads();
    const int oc = tid >> 2;
    const int op = tid & 3;
    u16* dst = out + (size_t)(c0 + oc) * R + r0 + op * 16;
    u16x8 v0, v1;
#pragma unroll
    for (int j = 0; j < 8; ++j) { v0[j] = tile[oc][op*16 + j]; v1[j] = tile[oc][op*16 + 8 + j]; }
    *(u16x8*)dst = v0;
    *(u16x8*)(dst + 8) = v1;
}

// ---------------- pipelined bf16 GEMM: dbuf LDS + raw s_barrier + fine vmcnt ----------------
// A: M x K bf16 row-major; Bt: N x K bf16 row-major; C: M x N.
// 128x128 tile, BK=32, 2-stage pipeline, lookahead 2. 4 glds/thread/stage.
// NOTE: always-issue prefetch overreads each A/B row by <=128 B -> keep buffers
// followed by other mapped workspace (they are).
// OUT: 1 = f32 * tanh(gate) store, 2 = bf16 store, 3 = atomic f32 (split-K)
template<int OUT>
__global__ void __launch_bounds__(256)
gemm_pipe_kernel(const u16* __restrict__ A, const u16* __restrict__ Bt,
                 void* __restrict__ Cp, int M, int N, int K, int kChunk,
                 const float* __restrict__ gate)
{
    constexpr int BM = 128, BN = 128, BK = 32;
    constexpr int STAGE = (BM + BN) * BK;        // 8192 u16 = 16 KB
    __shared__ u16 lds[2 * STAGE];               // 32 KB
    const int tid  = threadIdx.x;
    const int wave = tid >> 6;
    const int lane = tid & 63;
    const int m0   = blockIdx.x * BM;
    const int n0   = blockIdx.y * BN;
    const int kbeg = blockIdx.z * kChunk;
    const int wm = (wave & 1) * 64;
    const int wn = (wave >> 1) * 64;
    const int ml = lane & 15;
    const int quad = lane >> 4;

    f32x4 acc[4][4];
#pragma unroll
    for (int i = 0; i < 4; ++i)
#pragma unroll
        for (int j = 0; j < 4; ++j) acc[i][j] = (f32x4){0.f, 0.f, 0.f, 0.f};

    const u16* aptr = A  + (size_t)(m0 + (tid >> 2)) * K + kbeg + (tid & 3) * 8;
    const u16* bptr = Bt + (size_t)(n0 + (tid >> 2)) * K + kbeg + (tid & 3) * 8;
    const int aoff = wave * 512;                 // wave-uniform LDS base in A region
    const int boff = BM * BK + wave * 512;       // ... in B region

    // prologue: stage k=0 into buf0, k=BK into buf1  (8 outstanding / thread)
#pragma unroll
    for (int s = 0; s < 2; ++s) {
        u16* base = lds + s * STAGE;
        glds16(aptr + s * BK,             base + aoff);
        glds16(aptr + (size_t)64 * K + s * BK, base + aoff + 2048);
        glds16(bptr + s * BK,             base + boff);
        glds16(bptr + (size_t)64 * K + s * BK, base + boff + 2048);
    }

    for (int k0 = 0; k0 < kChunk; k0 += BK) {
        u16* cbase = lds + ((k0 / BK) & 1) * STAGE;
        // wait for the OLDEST stage's 4 loads only (next stage stays in flight)
        asm volatile("s_waitcnt vmcnt(4)" ::: "memory");
        asm volatile("s_barrier" ::: "memory");          // all waves: stage-k resident
        bf16x8 afr[4], bfr[4];
#pragma unroll
        for (int i = 0; i < 4; ++i)
            afr[i] = *(const bf16x8*)&cbase[(wm + i * 16 + ml) * BK + quad * 8];
#pragma unroll
        for (int j = 0; j < 4; ++j)
            bfr[j] = *(const bf16x8*)&cbase[BM * BK + (wn + j * 16 + ml) * BK + quad * 8];
        asm volatile("s_waitcnt lgkmcnt(0)" ::: "memory"); // frags in regs
        asm volatile("s_barrier" ::: "memory");            // safe to overwrite stage k
        {   // issue stage k+2 into the just-freed buffer (no wait)
            const int kn = k0 + 2 * BK;
            glds16(aptr + kn,                  cbase + aoff);
            glds16(aptr + (size_t)64 * K + kn, cbase + aoff + 2048);
            glds16(bptr + kn,                  cbase + boff);
            glds16(bptr + (size_t)64 * K + kn, cbase + boff + 2048);
        }
#pragma unroll
        for (int i = 0; i < 4; ++i)
#pragma unroll
            for (int j = 0; j < 4; ++j)
                acc[i][j] = __builtin_amdgcn_mfma_f32_16x16x32_bf16(afr[i], bfr[j], acc[i][j], 0, 0, 0);
    }
    asm volatile("s_waitcnt vmcnt(0)" ::: "memory");   // drain garbage prefetches before LDS dies

    float scl = 1.0f;
    if (OUT == 1) scl = tanhf(gate[0]);
    // C/D layout (m89/m91): col = lane&15, row = quad*4 + reg
#pragma unroll
    for (int i = 0; i < 4; ++i)
#pragma unroll
        for (int j = 0; j < 4; ++j)
#pragma unroll
            for (int rr = 0; rr < 4; ++rr) {
                int gr = m0 + wm + i * 16 + quad * 4 + rr;
                int gc = n0 + wn + j * 16 + ml;
                float val = acc[i][j][rr];
                if (OUT == 1)      ((float*)Cp)[(size_t)gr * N + gc] = val * scl;
                else if (OUT == 2) ((u16*)Cp)[(size_t)gr * N + gc] = f2bf(val);
                else               atomicAdd((float*)Cp + (size_t)gr * N + gc, val);
            }
}

// ---------------- counting sort of tokens by (b, channel) ----------------
__global__ void __launch_bounds__(256)
sort_kernel(const int* __restrict__ cmask, int* __restrict__ sorted,
            int4* __restrict__ tiles, int* __restrict__ ntiles)
{
    __shared__ int cnt[NBUCKET], cur[NBUCKET];
    int t = threadIdx.x;
    if (t < NBUCKET) cnt[t] = 0;
    __syncthreads();
    for (int i = t; i < MROWS; i += 256) {
        int bkt = ((i >> 10) << 3) | cmask[i];
        atomicAdd(&cnt[bkt], 1);
    }
    __syncthreads();
    if (t == 0) {
        int off = 0, nt = 0;
        for (int b2 = 0; b2 < NBUCKET; ++b2) {
            cur[b2] = off;
            for (int o = 0; o < cnt[b2]; o += TTILE)
                tiles[nt++] = make_int4(b2, off + o, min(TTILE, cnt[b2] - o), 0);
            off += cnt[b2];
        }
        *ntiles = nt;
    }
    __syncthreads();
    for (int i = t; i < MROWS; i += 256) {
        int bkt = ((i >> 10) << 3) | cmask[i];
        int pos = atomicAdd(&cur[bkt], 1);
        sorted[pos] = i;
    }
}

// ---------------- kv fp32 -> kb bf16 (as-is) + vt bf16 (transposed) ----------------
__global__ void __launch_bounds__(256)
kvcvt_kernel(const float* __restrict__ kvf, u16* __restrict__ kb, u16* __restrict__ vt)
{
    const int bn = blockIdx.x >> 2;
    const int g  = blockIdx.x & 3;
    const int t  = threadIdx.x;
#pragma unroll
    for (int i = 0; i < 16; ++i) {
        int flat = i * 256 + t;           // 0..4095
        int lat = flat >> 7, d = flat & 127;
        kb[(size_t)(bn * 32 + lat) * 512 + g * 128 + d] =
            f2bf(kvf[(size_t)(bn * 32 + lat) * 1024 + g * 128 + d]);
        int d2 = flat >> 5, lat2 = flat & 31;
        vt[((size_t)bn * 4 + g) * 4096 + d2 * 32 + lat2] =
            f2bf(kvf[(size_t)(bn * 32 + lat2) * 1024 + 512 + g * 128 + d2]);
    }
}

// ---------------- MFMA attention (round-2 verified): 8 tokens x 1 group per wave ----------------
// qb: (2048, 2048) bf16, col = g*512 + r*128 + d
// kb: (512 rows=(b,n,lat), 512 cols=g*128+d) bf16
// vt: ((b,n,g), d=128, lat=32) bf16
// yb: (2048, 2048) bf16
#define KSTR 136
#define VSTR 40
__global__ void __launch_bounds__(64)
attn_mfma_kernel(const u16* __restrict__ qb, const u16* __restrict__ kb,
                 const u16* __restrict__ vt, const int* __restrict__ sorted,
                 const int4* __restrict__ tiles, const int* __restrict__ ntiles,
                 u16* __restrict__ yb)
{
    const int tile = blockIdx.x;
    if (tile >= *ntiles) return;
    const int g = blockIdx.y;
    const int4 td = tiles[tile];
    const int bucket = td.x, start = td.y, cnt = td.z;
    const int lane = threadIdx.x;
    const int ml = lane & 15, quad = lane >> 4;

    __shared__ u16 k_lds[32 * KSTR];
    __shared__ u16 v_lds[128 * VSTR];
    __shared__ u16 p_lds[32 * VSTR];
    __shared__ int tok_s[TTILE];

    if (lane < TTILE) tok_s[lane] = (lane < cnt) ? sorted[start + lane] : -1;

    {
        const u16* ksrc = kb + (size_t)bucket * 32 * 512 + g * 128;
        const u16* vsrc = vt + ((size_t)bucket * 4 + g) * 4096;
#pragma unroll
        for (int rr = 0; rr < 8; ++rr) {
            int f = rr * 64 + lane;
            int krow = f >> 4, kc = (f & 15) * 8;
            *(u16x8*)&k_lds[krow * KSTR + kc] = *(const u16x8*)(ksrc + (size_t)krow * 512 + kc);
            int vd = f >> 2, vc = (f & 3) * 8;
            *(u16x8*)&v_lds[vd * VSTR + vc] = *(const u16x8*)(vsrc + (size_t)f * 8);
        }
    }
    __syncthreads();

    f32x4 sc[2][2];
#pragma unroll
    for (int i = 0; i < 2; ++i)
#pragma unroll
        for (int j = 0; j < 2; ++j) sc[i][j] = (f32x4){0.f, 0.f, 0.f, 0.f};
    const int tokA = tok_s[ml & 7];
    const u16* qrow = qb + (size_t)(tokA >= 0 ? tokA : 0) * 2048 + g * 512 + (ml >> 3) * 128;
#pragma unroll
    for (int s = 0; s < 4; ++s) {
        bf16x8 bfr0 = *(const bf16x8*)&k_lds[ml * KSTR + s * 32 + quad * 8];
        bf16x8 bfr1 = *(const bf16x8*)&k_lds[(16 + ml) * KSTR + s * 32 + quad * 8];
#pragma unroll
        for (int i = 0; i < 2; ++i) {
            bf16x8 afr = *(const bf16x8*)(qrow + i * 256 + s * 32 + quad * 8);
            sc[i][0] = __builtin_amdgcn_mfma_f32_16x16x32_bf16(afr, bfr0, sc[i][0], 0, 0, 0);
            sc[i][1] = __builtin_amdgcn_mfma_f32_16x16x32_bf16(afr, bfr1, sc[i][1], 0, 0, 0);
        }
    }

    const float scale = 0.088388347648318447f;   // 1/sqrt(128)
#pragma unroll
    for (int i = 0; i < 2; ++i)
#pragma unroll
        for (int reg = 0; reg < 4; ++reg) {
            float s0 = sc[i][0][reg] * scale;
            float s1 = sc[i][1][reg] * scale;
            float mx = fmaxf(s0, s1);
            mx = fmaxf(mx, __shfl_xor(mx, 1));
            mx = fmaxf(mx, __shfl_xor(mx, 2));
            mx = fmaxf(mx, __shfl_xor(mx, 4));
            mx = fmaxf(mx, __shfl_xor(mx, 8));
            float e0 = __expf(s0 - mx), e1 = __expf(s1 - mx);
            float sm = e0 + e1;
            sm += __shfl_xor(sm, 1);
            sm += __shfl_xor(sm, 2);
            sm += __shfl_xor(sm, 4);
            sm += __shfl_xor(sm, 8);
            float inv = 1.0f / sm;
            int prow = i * 16 + quad * 4 + reg;
            p_lds[prow * VSTR + ml]      = f2bf(e0 * inv);
            p_lds[prow * VSTR + 16 + ml] = f2bf(e1 * inv);
        }
    __syncthreads();

    bf16x8 pfr[2], vfr[8];
    pfr[0] = *(const bf16x8*)&p_lds[ml * VSTR + quad * 8];
    pfr[1] = *(const bf16x8*)&p_lds[(16 + ml) * VSTR + quad * 8];
#pragma unroll
    for (int j = 0; j < 8; ++j)
        vfr[j] = *(const bf16x8*)&v_lds[(j * 16 + ml) * VSTR + quad * 8];
#pragma unroll
    for (int i = 0; i < 2; ++i)
#pragma unroll
        for (int j = 0; j < 8; ++j) {
            f32x4 o = (f32x4){0.f, 0.f, 0.f, 0.f};
            o = __builtin_amdgcn_mfma_f32_16x16x32_bf16(pfr[i], vfr[j], o, 0, 0, 0);
#pragma unroll
            for (int reg = 0; reg < 4; ++reg) {
                int m = quad * 4 + reg;
                int tok = tok_s[m & 7];
                if (tok >= 0) {
                    int r = i * 2 + (m >> 3);
                    yb[(size_t)tok * 2048 + g * 512 + r * 128 + j * 16 + ml] = f2bf(o[reg]);
                }
            }
        }
}

extern "C" void kernel_launch(void* const* d_in, const int* in_sizes, int n_in,
                              void* d_out, int out_size, void* d_ws, size_t ws_size,
                              hipStream_t stream) {
    const float* x    = (const float*)d_in[0];
    const float* cs   = (const float*)d_in[1];
    const int*   cm   = (const int*)d_in[2];
    const float* Wq   = (const float*)d_in[3];
    const float* Wk   = (const float*)d_in[4];
    const float* Wv   = (const float*)d_in[5];
    const float* Wo   = (const float*)d_in[6];
    const float* gate = (const float*)d_in[7];
    float* out = (float*)d_out;

    // workspace layout (16B aligned). Every GEMM A/Bt buffer is followed by
    // more mapped workspace (pipelined prefetch overreads <=128 B).
    char* w = (char*)d_ws;
    u16* xb   = (u16*)w;  w += (size_t)MROWS * CC * 2;        // 8.4 MB
    u16* wqt  = (u16*)w;  w += (size_t)CC * CC * 2;           // 8.4 MB
    u16* wot  = (u16*)w;  w += (size_t)CC * CC * 2;           // 8.4 MB
    u16* qb   = (u16*)w;  w += (size_t)MROWS * CC * 2;        // 8.4 MB
    u16* yb   = (u16*)w;  w += (size_t)MROWS * CC * 2;        // 8.4 MB
    u16* csb  = (u16*)w;  w += (size_t)CSROWS * CC * 2;       // 2.1 MB
    u16* wkvt = (u16*)w;  w += (size_t)1024 * CC * 2;         // 4.2 MB
    float* kvf = (float*)w; w += (size_t)CSROWS * 1024 * 4;   // 2.1 MB
    u16* kb   = (u16*)w;  w += (size_t)CSROWS * 512 * 2;      // 0.5 MB
    u16* vt   = (u16*)w;  w += (size_t)64 * 128 * 32 * 2;     // 0.5 MB
    int* sorted = (int*)w; w += (size_t)MROWS * 4;
    int4* tiles = (int4*)w; w += (size_t)MAXTILES * 16;
    int* ntiles = (int*)w;  w += 4096;                        // + overread pad

    // ---- KV pipeline ----
    hipMemsetAsync(kvf, 0, (size_t)CSROWS * 1024 * 4, stream);
    sort_kernel<<<1, 256, 0, stream>>>(cm, sorted, tiles, ntiles);
    cvt_bf16_kernel<<<(CSROWS * CC) / 2048, 256, 0, stream>>>(cs, csb, CSROWS * CC);
    tcvt_kernel<<<dim3(512 / 64, CC / 64), 256, 0, stream>>>(Wk, wkvt, CC, 512);
    tcvt_kernel<<<dim3(512 / 64, CC / 64), 256, 0, stream>>>(Wv, wkvt + (size_t)512 * CC, CC, 512);
    // kv = cs @ [Wk|Wv], split-K=8 (grid 4x8x8 = 256 blocks)
    gemm_pipe_kernel<3><<<dim3(CSROWS / 128, 1024 / 128, 8), 256, 0, stream>>>(
        csb, wkvt, kvf, CSROWS, 1024, CC, CC / 8, nullptr);
    kvcvt_kernel<<<64, 256, 0, stream>>>(kvf, kb, vt);

    // ---- Q pipeline ----
    cvt_bf16_kernel<<<(MROWS * CC) / 2048, 256, 0, stream>>>(x, xb, MROWS * CC);
    tcvt_kernel<<<dim3(CC / 64, CC / 64), 256, 0, stream>>>(Wq, wqt, CC, CC);
    // q = x @ Wq -> bf16 (grid 16x16)
    gemm_pipe_kernel<2><<<dim3(MROWS / 128, CC / 128), 256, 0, stream>>>(
        xb, wqt, qb, MROWS, CC, CC, CC, nullptr);

    // ---- attention + output ----
    tcvt_kernel<<<dim3(CC / 64, CC / 64), 256, 0, stream>>>(Wo, wot, CC, CC);
    attn_mfma_kernel<<<dim3(MAXTILES, 4), 64, 0, stream>>>(qb, kb, vt, sorted, tiles, ntiles, yb);
    // out = (y @ Wo) * tanh(gate) (grid 16x16)
    gemm_pipe_kernel<1><<<dim3(MROWS / 128, CC / 128), 256, 0, stream>>>(
        yb, wot, out, MROWS, CC, CC, CC, gate);
}

// Round 5
// 199.847 us; speedup vs baseline: 1.4398x; 1.1927x over previous
//
#include <hip/hip_runtime.h>
#include <hip/hip_bf16.h>

// Problem constants (from reference)
#define BB 2
#define TT 1024
#define CC 2048
#define NCH 8
#define KLAT 32
#define NKV 4
#define NREP 4
#define DD 128
#define MROWS (BB*TT)          // 2048
#define CSROWS (BB*NCH*KLAT)   // 512
#define NBUCKET 16             // B * NCH
#define TTILE 8                // tokens per attention tile
#define MAXTILES (MROWS/TTILE + NBUCKET)   // 272

typedef unsigned short u16;
typedef __attribute__((ext_vector_type(8))) short bf16x8;   // MFMA A/B frag (4 VGPRs)
typedef __attribute__((ext_vector_type(4))) float f32x4;    // MFMA C/D frag
typedef __attribute__((ext_vector_type(8))) u16 u16x8;

__device__ __forceinline__ u16 f2bf(float f) {
    unsigned int u = __builtin_bit_cast(unsigned int, f);
    u = (u + 0x7FFFu + ((u >> 16) & 1u)) >> 16;   // RNE; inputs finite
    return (u16)u;
}

// async global->LDS, 16B per lane. LDS dest = wave-uniform base + lane*16.
__device__ __forceinline__ void glds16(const u16* g, u16* l) {
    __builtin_amdgcn_global_load_lds(
        (const __attribute__((address_space(1))) void*)g,
        (__attribute__((address_space(3))) void*)l, 16, 0, 0);
}

// ================= prep: sort + converts + weight transposes, one launch =================
// section bases (256 threads/block):
#define PB_SORT 0
#define PB_X    1                       // 2048 blocks: cvt x
#define PB_CS   (PB_X + 2048)           // 512: cvt cs
#define PB_WQ   (PB_CS + 512)           // 1024: tcvt Wq (32 x 32)
#define PB_WK   (PB_WQ + 1024)          // 256:  tcvt Wk (8 x 32)
#define PB_WV   (PB_WK + 256)           // 256:  tcvt Wv (8 x 32)
#define PB_WO   (PB_WV + 256)           // 1024: tcvt Wo (32 x 32)
#define PB_END  (PB_WO + 1024)          // 5121

__device__ __forceinline__ void cvt_body(const float* __restrict__ in, u16* __restrict__ out,
                                         int blk, int tid) {
    int i = (blk * 256 + tid) * 8;
    float4 a = *(const float4*)(in + i);
    float4 b = *(const float4*)(in + i + 4);
    u16x8 o;
    o[0]=f2bf(a.x); o[1]=f2bf(a.y); o[2]=f2bf(a.z); o[3]=f2bf(a.w);
    o[4]=f2bf(b.x); o[5]=f2bf(b.y); o[6]=f2bf(b.z); o[7]=f2bf(b.w);
    *(u16x8*)(out + i) = o;
}

__device__ __forceinline__ void tcvt_body(const float* __restrict__ in, u16* __restrict__ out,
                                          int R, int C, int bx, int by, int tid,
                                          u16 (*tile)[65]) {
    const int c0 = bx * 64, r0 = by * 64;
    const int tx = tid & 15, ty = tid >> 4;
#pragma unroll
    for (int p = 0; p < 4; ++p) {
        int r = p * 16 + ty;
        float4 v = *(const float4*)(in + (size_t)(r0 + r) * C + c0 + tx * 4);
        tile[tx*4+0][r] = f2bf(v.x);
        tile[tx*4+1][r] = f2bf(v.y);
        tile[tx*4+2][r] = f2bf(v.z);
        tile[tx*4+3][r] = f2bf(v.w);
    }
    __syncthreads();
    const int oc = tid >> 2, op = tid & 3;
    u16* dst = out + (size_t)(c0 + oc) * R + r0 + op * 16;
    u16x8 v0, v1;
#pragma unroll
    for (int j = 0; j < 8; ++j) { v0[j] = tile[oc][op*16 + j]; v1[j] = tile[oc][op*16 + 8 + j]; }
    *(u16x8*)dst = v0;
    *(u16x8*)(dst + 8) = v1;
}

__global__ void __launch_bounds__(256)
prep_kernel(const float* __restrict__ x, const float* __restrict__ cs,
            const int* __restrict__ cm,
            const float* __restrict__ Wq, const float* __restrict__ Wk,
            const float* __restrict__ Wv, const float* __restrict__ Wo,
            u16* __restrict__ xb, u16* __restrict__ csb,
            u16* __restrict__ wqt, u16* __restrict__ wkvt, u16* __restrict__ wot,
            int* __restrict__ sorted, int4* __restrict__ tiles, int* __restrict__ ntiles)
{
    __shared__ u16 tile[64][65];
    __shared__ int cnt[NBUCKET], cur[NBUCKET];
    const int bid = blockIdx.x;
    const int tid = threadIdx.x;

    if (bid == PB_SORT) {
        if (tid < NBUCKET) cnt[tid] = 0;
        __syncthreads();
        for (int i = tid; i < MROWS; i += 256) {
            int bkt = ((i >> 10) << 3) | cm[i];
            atomicAdd(&cnt[bkt], 1);
        }
        __syncthreads();
        if (tid == 0) {
            int off = 0, nt = 0;
            for (int b2 = 0; b2 < NBUCKET; ++b2) {
                cur[b2] = off;
                for (int o = 0; o < cnt[b2]; o += TTILE)
                    tiles[nt++] = make_int4(b2, off + o, min(TTILE, cnt[b2] - o), 0);
                off += cnt[b2];
            }
            *ntiles = nt;
        }
        __syncthreads();
        for (int i = tid; i < MROWS; i += 256) {
            int bkt = ((i >> 10) << 3) | cm[i];
            int pos = atomicAdd(&cur[bkt], 1);
            sorted[pos] = i;
        }
    } else if (bid < PB_CS) {
        cvt_body(x, xb, bid - PB_X, tid);
    } else if (bid < PB_WQ) {
        cvt_body(cs, csb, bid - PB_CS, tid);
    } else if (bid < PB_WK) {
        int b2 = bid - PB_WQ;
        tcvt_body(Wq, wqt, CC, CC, b2 & 31, b2 >> 5, tid, tile);
    } else if (bid < PB_WV) {
        int b2 = bid - PB_WK;
        tcvt_body(Wk, wkvt, CC, 512, b2 & 7, b2 >> 3, tid, tile);
    } else if (bid < PB_WO) {
        int b2 = bid - PB_WV;
        tcvt_body(Wv, wkvt + (size_t)512 * CC, CC, 512, b2 & 7, b2 >> 3, tid, tile);
    } else {
        int b2 = bid - PB_WO;
        tcvt_body(Wo, wot, CC, CC, b2 & 31, b2 >> 5, tid, tile);
    }
}

// ================= pipelined bf16 GEMM core (dbuf LDS, raw s_barrier, fine vmcnt) =================
// A/Bt pre-offset to the block's panel start (row-major, K=2048 contiguous).
// 128x128 tile, BK=32, 2-stage pipeline. Overreads <=128 B past each panel.
#define GK 2048
__device__ __forceinline__ void gemm_core(const u16* __restrict__ A, const u16* __restrict__ Bt,
                                          u16* lds, f32x4 (*acc)[4])
{
    constexpr int BK = 32, STAGE = 8192;   // (128+128)*32 u16
    const int tid  = threadIdx.x;
    const int wave = tid >> 6;
    const int lane = tid & 63;
    const int wm = (wave & 1) * 64;
    const int wn = (wave >> 1) * 64;
    const int ml = lane & 15;
    const int quad = lane >> 4;

#pragma unroll
    for (int i = 0; i < 4; ++i)
#pragma unroll
        for (int j = 0; j < 4; ++j) acc[i][j] = (f32x4){0.f, 0.f, 0.f, 0.f};

    const u16* aptr = A  + (size_t)(tid >> 2) * GK + (tid & 3) * 8;
    const u16* bptr = Bt + (size_t)(tid >> 2) * GK + (tid & 3) * 8;
    const int aoff = wave * 512;
    const int boff = 128 * BK + wave * 512;

#pragma unroll
    for (int s = 0; s < 2; ++s) {
        u16* base = lds + s * STAGE;
        glds16(aptr + s * BK,                   base + aoff);
        glds16(aptr + (size_t)64 * GK + s * BK, base + aoff + 2048);
        glds16(bptr + s * BK,                   base + boff);
        glds16(bptr + (size_t)64 * GK + s * BK, base + boff + 2048);
    }

    for (int k0 = 0; k0 < GK; k0 += BK) {
        u16* cbase = lds + ((k0 / BK) & 1) * STAGE;
        asm volatile("s_waitcnt vmcnt(4)" ::: "memory");   // oldest stage resident
        asm volatile("s_barrier" ::: "memory");
        bf16x8 afr[4], bfr[4];
#pragma unroll
        for (int i = 0; i < 4; ++i)
            afr[i] = *(const bf16x8*)&cbase[(wm + i * 16 + ml) * BK + quad * 8];
#pragma unroll
        for (int j = 0; j < 4; ++j)
            bfr[j] = *(const bf16x8*)&cbase[128 * BK + (wn + j * 16 + ml) * BK + quad * 8];
        asm volatile("s_waitcnt lgkmcnt(0)" ::: "memory");
        asm volatile("s_barrier" ::: "memory");            // stage-k buffer free
        {
            const int kn = k0 + 2 * BK;                    // overreads <=128B at tail
            glds16(aptr + kn,                   cbase + aoff);
            glds16(aptr + (size_t)64 * GK + kn, cbase + aoff + 2048);
            glds16(bptr + kn,                   cbase + boff);
            glds16(bptr + (size_t)64 * GK + kn, cbase + boff + 2048);
        }
#pragma unroll
        for (int i = 0; i < 4; ++i)
#pragma unroll
            for (int j = 0; j < 4; ++j)
                acc[i][j] = __builtin_amdgcn_mfma_f32_16x16x32_bf16(afr[i], bfr[j], acc[i][j], 0, 0, 0);
    }
    asm volatile("s_waitcnt vmcnt(0)" ::: "memory");   // drain garbage prefetches
}

// ---------------- merged q-GEMM (256 blocks) + kv-GEMM (32 blocks) ----------------
// q:  qb[m][n] = bf16(x @ Wq),        m0=(bid&15)*128, n0=(bid>>4)*128
// kv: cs @ [Wk|Wv]; n<512 -> kb[m][n]; n>=512 -> vt[(bn*4+g)][d][lat] (transposed epilogue)
__global__ void __launch_bounds__(256)
gemm_qkv_kernel(const u16* __restrict__ xb, const u16* __restrict__ wqt, u16* __restrict__ qb,
                const u16* __restrict__ csb, const u16* __restrict__ wkvt,
                u16* __restrict__ kb, u16* __restrict__ vt)
{
    constexpr int STAGE = 8192;
    __shared__ u16 lds[2 * STAGE];
    const int bid = blockIdx.x;
    const int tid = threadIdx.x;
    const int wave = tid >> 6, lane = tid & 63;
    const int wm = (wave & 1) * 64, wn = (wave >> 1) * 64;
    const int ml = lane & 15, quad = lane >> 4;
    const bool isQ = bid < 256;
    const u16 *A, *Bt;
    int m0, n0;
    if (isQ) { m0 = (bid & 15) * 128; n0 = (bid >> 4) * 128; A = xb + (size_t)m0 * GK; Bt = wqt + (size_t)n0 * GK; }
    else     { int b2 = bid - 256; m0 = (b2 & 3) * 128; n0 = (b2 >> 2) * 128; A = csb + (size_t)m0 * GK; Bt = wkvt + (size_t)n0 * GK; }

    f32x4 acc[4][4];
    gemm_core(A, Bt, lds, acc);

#pragma unroll
    for (int i = 0; i < 4; ++i)
#pragma unroll
        for (int j = 0; j < 4; ++j)
#pragma unroll
            for (int rr = 0; rr < 4; ++rr) {
                int gr = m0 + wm + i * 16 + quad * 4 + rr;
                int gc = n0 + wn + j * 16 + ml;
                float val = acc[i][j][rr];
                if (isQ) {
                    qb[(size_t)gr * 2048 + gc] = f2bf(val);
                } else if (gc < 512) {
                    kb[(size_t)gr * 512 + gc] = f2bf(val);
                } else {
                    int g = (gc - 512) >> 7, d = (gc - 512) & 127;
                    int bn = gr >> 5, lat = gr & 31;
                    vt[(((size_t)bn * 4 + g) << 12) + (d << 5) + lat] = f2bf(val);
                }
            }
}

// ---------------- out = (y @ Wo) * tanh(gate) ----------------
__global__ void __launch_bounds__(256)
gemm_out_kernel(const u16* __restrict__ yb, const u16* __restrict__ wot,
                float* __restrict__ out, const float* __restrict__ gate)
{
    constexpr int STAGE = 8192;
    __shared__ u16 lds[2 * STAGE];
    const int tid = threadIdx.x;
    const int wave = tid >> 6, lane = tid & 63;
    const int wm = (wave & 1) * 64, wn = (wave >> 1) * 64;
    const int ml = lane & 15, quad = lane >> 4;
    const int m0 = blockIdx.x * 128, n0 = blockIdx.y * 128;

    f32x4 acc[4][4];
    gemm_core(yb + (size_t)m0 * GK, wot + (size_t)n0 * GK, lds, acc);

    const float scl = tanhf(gate[0]);
#pragma unroll
    for (int i = 0; i < 4; ++i)
#pragma unroll
        for (int j = 0; j < 4; ++j)
#pragma unroll
            for (int rr = 0; rr < 4; ++rr) {
                int gr = m0 + wm + i * 16 + quad * 4 + rr;
                int gc = n0 + wn + j * 16 + ml;
                out[(size_t)gr * 2048 + gc] = acc[i][j][rr] * scl;
            }
}

// ---------------- MFMA attention (verified): 8 tokens x 1 group per wave ----------------
#define KSTR 136
#define VSTR 40
__global__ void __launch_bounds__(64)
attn_mfma_kernel(const u16* __restrict__ qb, const u16* __restrict__ kb,
                 const u16* __restrict__ vt, const int* __restrict__ sorted,
                 const int4* __restrict__ tiles, const int* __restrict__ ntiles,
                 u16* __restrict__ yb)
{
    const int tile = blockIdx.x;
    if (tile >= *ntiles) return;
    const int g = blockIdx.y;
    const int4 td = tiles[tile];
    const int bucket = td.x, start = td.y, cnt = td.z;
    const int lane = threadIdx.x;
    const int ml = lane & 15, quad = lane >> 4;

    __shared__ u16 k_lds[32 * KSTR];
    __shared__ u16 v_lds[128 * VSTR];
    __shared__ u16 p_lds[32 * VSTR];
    __shared__ int tok_s[TTILE];

    if (lane < TTILE) tok_s[lane] = (lane < cnt) ? sorted[start + lane] : -1;

    {
        const u16* ksrc = kb + (size_t)bucket * 32 * 512 + g * 128;
        const u16* vsrc = vt + ((size_t)bucket * 4 + g) * 4096;
#pragma unroll
        for (int rr = 0; rr < 8; ++rr) {
            int f = rr * 64 + lane;
            int krow = f >> 4, kc = (f & 15) * 8;
            *(u16x8*)&k_lds[krow * KSTR + kc] = *(const u16x8*)(ksrc + (size_t)krow * 512 + kc);
            int vd = f >> 2, vc = (f & 3) * 8;
            *(u16x8*)&v_lds[vd * VSTR + vc] = *(const u16x8*)(vsrc + (size_t)f * 8);
        }
    }
    __syncthreads();

    f32x4 sc[2][2];
#pragma unroll
    for (int i = 0; i < 2; ++i)
#pragma unroll
        for (int j = 0; j < 2; ++j) sc[i][j] = (f32x4){0.f, 0.f, 0.f, 0.f};
    const int tokA = tok_s[ml & 7];
    const u16* qrow = qb + (size_t)(tokA >= 0 ? tokA : 0) * 2048 + g * 512 + (ml >> 3) * 128;
#pragma unroll
    for (int s = 0; s < 4; ++s) {
        bf16x8 bfr0 = *(const bf16x8*)&k_lds[ml * KSTR + s * 32 + quad * 8];
        bf16x8 bfr1 = *(const bf16x8*)&k_lds[(16 + ml) * KSTR + s * 32 + quad * 8];
#pragma unroll
        for (int i = 0; i < 2; ++i) {
            bf16x8 afr = *(const bf16x8*)(qrow + i * 256 + s * 32 + quad * 8);
            sc[i][0] = __builtin_amdgcn_mfma_f32_16x16x32_bf16(afr, bfr0, sc[i][0], 0, 0, 0);
            sc[i][1] = __builtin_amdgcn_mfma_f32_16x16x32_bf16(afr, bfr1, sc[i][1], 0, 0, 0);
        }
    }

    const float scale = 0.088388347648318447f;   // 1/sqrt(128)
#pragma unroll
    for (int i = 0; i < 2; ++i)
#pragma unroll
        for (int reg = 0; reg < 4; ++reg) {
            float s0 = sc[i][0][reg] * scale;
            float s1 = sc[i][1][reg] * scale;
            float mx = fmaxf(s0, s1);
            mx = fmaxf(mx, __shfl_xor(mx, 1));
            mx = fmaxf(mx, __shfl_xor(mx, 2));
            mx = fmaxf(mx, __shfl_xor(mx, 4));
            mx = fmaxf(mx, __shfl_xor(mx, 8));
            float e0 = __expf(s0 - mx), e1 = __expf(s1 - mx);
            float sm = e0 + e1;
            sm += __shfl_xor(sm, 1);
            sm += __shfl_xor(sm, 2);
            sm += __shfl_xor(sm, 4);
            sm += __shfl_xor(sm, 8);
            float inv = 1.0f / sm;
            int prow = i * 16 + quad * 4 + reg;
            p_lds[prow * VSTR + ml]      = f2bf(e0 * inv);
            p_lds[prow * VSTR + 16 + ml] = f2bf(e1 * inv);
        }
    __syncthreads();

    bf16x8 pfr[2], vfr[8];
    pfr[0] = *(const bf16x8*)&p_lds[ml * VSTR + quad * 8];
    pfr[1] = *(const bf16x8*)&p_lds[(16 + ml) * VSTR + quad * 8];
#pragma unroll
    for (int j = 0; j < 8; ++j)
        vfr[j] = *(const bf16x8*)&v_lds[(j * 16 + ml) * VSTR + quad * 8];
#pragma unroll
    for (int i = 0; i < 2; ++i)
#pragma unroll
        for (int j = 0; j < 8; ++j) {
            f32x4 o = (f32x4){0.f, 0.f, 0.f, 0.f};
            o = __builtin_amdgcn_mfma_f32_16x16x32_bf16(pfr[i], vfr[j], o, 0, 0, 0);
#pragma unroll
            for (int reg = 0; reg < 4; ++reg) {
                int m = quad * 4 + reg;
                int tok = tok_s[m & 7];
                if (tok >= 0) {
                    int r = i * 2 + (m >> 3);
                    yb[(size_t)tok * 2048 + g * 512 + r * 128 + j * 16 + ml] = f2bf(o[reg]);
                }
            }
        }
}

extern "C" void kernel_launch(void* const* d_in, const int* in_sizes, int n_in,
                              void* d_out, int out_size, void* d_ws, size_t ws_size,
                              hipStream_t stream) {
    const float* x    = (const float*)d_in[0];
    const float* cs   = (const float*)d_in[1];
    const int*   cm   = (const int*)d_in[2];
    const float* Wq   = (const float*)d_in[3];
    const float* Wk   = (const float*)d_in[4];
    const float* Wv   = (const float*)d_in[5];
    const float* Wo   = (const float*)d_in[6];
    const float* gate = (const float*)d_in[7];
    float* out = (float*)d_out;

    // workspace layout (16B aligned). Every GEMM A/Bt panel is followed by
    // more mapped workspace (pipelined prefetch overreads <=128 B).
    char* w = (char*)d_ws;
    u16* xb   = (u16*)w;  w += (size_t)MROWS * CC * 2;        // 8.4 MB
    u16* wqt  = (u16*)w;  w += (size_t)CC * CC * 2;           // 8.4 MB
    u16* wot  = (u16*)w;  w += (size_t)CC * CC * 2;           // 8.4 MB
    u16* qb   = (u16*)w;  w += (size_t)MROWS * CC * 2;        // 8.4 MB
    u16* yb   = (u16*)w;  w += (size_t)MROWS * CC * 2;        // 8.4 MB
    u16* csb  = (u16*)w;  w += (size_t)CSROWS * CC * 2;       // 2.1 MB
    u16* wkvt = (u16*)w;  w += (size_t)1024 * CC * 2;         // 4.2 MB
    u16* kb   = (u16*)w;  w += (size_t)CSROWS * 512 * 2;      // 0.5 MB
    u16* vt   = (u16*)w;  w += (size_t)64 * 128 * 32 * 2;     // 0.5 MB
    int* sorted = (int*)w; w += (size_t)MROWS * 4;
    int4* tiles = (int4*)w; w += (size_t)MAXTILES * 16;
    int* ntiles = (int*)w;  w += 4096;                        // + overread pad

    // 1) all preprocessing in one launch
    prep_kernel<<<PB_END, 256, 0, stream>>>(x, cs, cm, Wq, Wk, Wv, Wo,
                                            xb, csb, wqt, wkvt, wot,
                                            sorted, tiles, ntiles);
    // 2) q-GEMM + kv-GEMM merged (kv epilogue writes kb/vt directly)
    gemm_qkv_kernel<<<288, 256, 0, stream>>>(xb, wqt, qb, csb, wkvt, kb, vt);
    // 3) attention
    attn_mfma_kernel<<<dim3(MAXTILES, 4), 64, 0, stream>>>(qb, kb, vt, sorted, tiles, ntiles, yb);
    // 4) out = (y @ Wo) * tanh(gate)
    gemm_out_kernel<<<dim3(16, 16), 256, 0, stream>>>(yb, wot, out, gate);
}

// Round 6
// 196.625 us; speedup vs baseline: 1.4634x; 1.0164x over previous
//
#include <hip/hip_runtime.h>
#include <hip/hip_bf16.h>

// Problem constants (from reference)
#define BB 2
#define TT 1024
#define CC 2048
#define NCH 8
#define KLAT 32
#define NKV 4
#define NREP 4
#define DD 128
#define MROWS (BB*TT)          // 2048
#define CSROWS (BB*NCH*KLAT)   // 512
#define NBUCKET 16             // B * NCH
#define TTILE 8                // tokens per attention tile
#define MAXTILES (MROWS/TTILE + NBUCKET)   // 272

typedef unsigned short u16;
typedef __attribute__((ext_vector_type(8))) short bf16x8;   // MFMA A/B frag (4 VGPRs)
typedef __attribute__((ext_vector_type(4))) float f32x4;    // MFMA C/D frag
typedef __attribute__((ext_vector_type(8))) u16 u16x8;

__device__ __forceinline__ u16 f2bf(float f) {
    unsigned int u = __builtin_bit_cast(unsigned int, f);
    u = (u + 0x7FFFu + ((u >> 16) & 1u)) >> 16;   // RNE; inputs finite
    return (u16)u;
}

// async global->LDS, 16B per lane. LDS dest = wave-uniform base + lane*16.
__device__ __forceinline__ void glds16(const u16* g, u16* l) {
    __builtin_amdgcn_global_load_lds(
        (const __attribute__((address_space(1))) void*)g,
        (__attribute__((address_space(3))) void*)l, 16, 0, 0);
}

// ================= prep: sort + converts + weight transposes, one launch =================
#define PB_SORT 0
#define PB_X    1                       // 2048 blocks: cvt x
#define PB_CS   (PB_X + 2048)           // 512: cvt cs
#define PB_WQ   (PB_CS + 512)           // 1024: tcvt Wq (32 x 32)
#define PB_WK   (PB_WQ + 1024)          // 256:  tcvt Wk (8 x 32)
#define PB_WV   (PB_WK + 256)           // 256:  tcvt Wv (8 x 32)
#define PB_WO   (PB_WV + 256)           // 1024: tcvt Wo (32 x 32)
#define PB_END  (PB_WO + 1024)          // 5121

__device__ __forceinline__ void cvt_body(const float* __restrict__ in, u16* __restrict__ out,
                                         int blk, int tid) {
    int i = (blk * 256 + tid) * 8;
    float4 a = *(const float4*)(in + i);
    float4 b = *(const float4*)(in + i + 4);
    u16x8 o;
    o[0]=f2bf(a.x); o[1]=f2bf(a.y); o[2]=f2bf(a.z); o[3]=f2bf(a.w);
    o[4]=f2bf(b.x); o[5]=f2bf(b.y); o[6]=f2bf(b.z); o[7]=f2bf(b.w);
    *(u16x8*)(out + i) = o;
}

__device__ __forceinline__ void tcvt_body(const float* __restrict__ in, u16* __restrict__ out,
                                          int R, int C, int bx, int by, int tid,
                                          u16 (*tile)[65]) {
    const int c0 = bx * 64, r0 = by * 64;
    const int tx = tid & 15, ty = tid >> 4;
#pragma unroll
    for (int p = 0; p < 4; ++p) {
        int r = p * 16 + ty;
        float4 v = *(const float4*)(in + (size_t)(r0 + r) * C + c0 + tx * 4);
        tile[tx*4+0][r] = f2bf(v.x);
        tile[tx*4+1][r] = f2bf(v.y);
        tile[tx*4+2][r] = f2bf(v.z);
        tile[tx*4+3][r] = f2bf(v.w);
    }
    __syncthreads();
    const int oc = tid >> 2, op = tid & 3;
    u16* dst = out + (size_t)(c0 + oc) * R + r0 + op * 16;
    u16x8 v0, v1;
#pragma unroll
    for (int j = 0; j < 8; ++j) { v0[j] = tile[oc][op*16 + j]; v1[j] = tile[oc][op*16 + 8 + j]; }
    *(u16x8*)dst = v0;
    *(u16x8*)(dst + 8) = v1;
}

__global__ void __launch_bounds__(256)
prep_kernel(const float* __restrict__ x, const float* __restrict__ cs,
            const int* __restrict__ cm,
            const float* __restrict__ Wq, const float* __restrict__ Wk,
            const float* __restrict__ Wv, const float* __restrict__ Wo,
            u16* __restrict__ xb, u16* __restrict__ csb,
            u16* __restrict__ wqt, u16* __restrict__ wkvt, u16* __restrict__ wot,
            int* __restrict__ sorted, int4* __restrict__ tiles, int* __restrict__ ntiles)
{
    __shared__ u16 tile[64][65];
    __shared__ int cnt[NBUCKET], cur[NBUCKET];
    const int bid = blockIdx.x;
    const int tid = threadIdx.x;

    if (bid == PB_SORT) {
        if (tid < NBUCKET) cnt[tid] = 0;
        __syncthreads();
        for (int i = tid; i < MROWS; i += 256) {
            int bkt = ((i >> 10) << 3) | cm[i];
            atomicAdd(&cnt[bkt], 1);
        }
        __syncthreads();
        if (tid == 0) {
            int off = 0, nt = 0;
            for (int b2 = 0; b2 < NBUCKET; ++b2) {
                cur[b2] = off;
                for (int o = 0; o < cnt[b2]; o += TTILE)
                    tiles[nt++] = make_int4(b2, off + o, min(TTILE, cnt[b2] - o), 0);
                off += cnt[b2];
            }
            *ntiles = nt;
        }
        __syncthreads();
        for (int i = tid; i < MROWS; i += 256) {
            int bkt = ((i >> 10) << 3) | cm[i];
            int pos = atomicAdd(&cur[bkt], 1);
            sorted[pos] = i;
        }
    } else if (bid < PB_CS) {
        cvt_body(x, xb, bid - PB_X, tid);
    } else if (bid < PB_WQ) {
        cvt_body(cs, csb, bid - PB_CS, tid);
    } else if (bid < PB_WK) {
        int b2 = bid - PB_WQ;
        tcvt_body(Wq, wqt, CC, CC, b2 & 31, b2 >> 5, tid, tile);
    } else if (bid < PB_WV) {
        int b2 = bid - PB_WK;
        tcvt_body(Wk, wkvt, CC, 512, b2 & 7, b2 >> 3, tid, tile);
    } else if (bid < PB_WO) {
        int b2 = bid - PB_WV;
        tcvt_body(Wv, wkvt + (size_t)512 * CC, CC, 512, b2 & 7, b2 >> 3, tid, tile);
    } else {
        int b2 = bid - PB_WO;
        tcvt_body(Wo, wot, CC, CC, b2 & 31, b2 >> 5, tid, tile);
    }
}

// ========== 4-stage single-barrier pipelined bf16 GEMM core ==========
// A/Bt pre-offset to block panel start (row-major, K=2048 contiguous).
// 128x128 tile, BK=32, 4 LDS buffers (64 KB), lookahead 3 stages.
// Safety: glds at iter k overwrites buf (k-1)%4; every wave past barrier(k)
// has lgkm-waited its stage-(k-1) ds_reads (they feed MFMA(k-1), which
// precedes barrier(k) in program order) -> no WAR race, one barrier/iter.
// Overreads <=3*BK*2=192 B past each panel row (buffers have mapped pads).
#define GK 2048
__device__ __forceinline__ void gemm_core(const u16* __restrict__ A, const u16* __restrict__ Bt,
                                          u16* lds, f32x4 (*acc)[4])
{
    constexpr int BK = 32, STAGE = 8192;   // (128+128)*32 u16 = 16 KB
    const int tid  = threadIdx.x;
    const int wave = tid >> 6;
    const int lane = tid & 63;
    const int wm = (wave & 1) * 64;
    const int wn = (wave >> 1) * 64;
    const int ml = lane & 15;
    const int quad = lane >> 4;

#pragma unroll
    for (int i = 0; i < 4; ++i)
#pragma unroll
        for (int j = 0; j < 4; ++j) acc[i][j] = (f32x4){0.f, 0.f, 0.f, 0.f};

    const u16* aptr = A  + (size_t)(tid >> 2) * GK + (tid & 3) * 8;
    const u16* bptr = Bt + (size_t)(tid >> 2) * GK + (tid & 3) * 8;
    const int aoff = wave * 512;
    const int boff = 128 * BK + wave * 512;

    // prologue: stages 0,1,2 (12 outstanding loads / wave)
#pragma unroll
    for (int s = 0; s < 3; ++s) {
        u16* base = lds + s * STAGE;
        glds16(aptr + s * BK,                   base + aoff);
        glds16(aptr + (size_t)64 * GK + s * BK, base + aoff + 2048);
        glds16(bptr + s * BK,                   base + boff);
        glds16(bptr + (size_t)64 * GK + s * BK, base + boff + 2048);
    }

    for (int k0 = 0; k0 < GK; k0 += BK) {
        u16* cbase = lds + ((k0 / BK) & 3) * STAGE;
        asm volatile("s_waitcnt vmcnt(8)" ::: "memory");   // oldest stage resident
        asm volatile("s_barrier" ::: "memory");            // all waves: stage k in LDS,
                                                           // all stage-(k-1) reads done
        {   // issue stage k+3 into buf (k+3)%4 == (k-1)%4 (just freed)
            const int kn = k0 + 3 * BK;                    // tail overread <=192 B
            u16* nbase = lds + (((k0 / BK) + 3) & 3) * STAGE;
            glds16(aptr + kn,                   nbase + aoff);
            glds16(aptr + (size_t)64 * GK + kn, nbase + aoff + 2048);
            glds16(bptr + kn,                   nbase + boff);
            glds16(bptr + (size_t)64 * GK + kn, nbase + boff + 2048);
        }
        bf16x8 afr[4], bfr[4];
#pragma unroll
        for (int i = 0; i < 4; ++i)
            afr[i] = *(const bf16x8*)&cbase[(wm + i * 16 + ml) * BK + quad * 8];
#pragma unroll
        for (int j = 0; j < 4; ++j)
            bfr[j] = *(const bf16x8*)&cbase[128 * BK + (wn + j * 16 + ml) * BK + quad * 8];
#pragma unroll
        for (int i = 0; i < 4; ++i)
#pragma unroll
            for (int j = 0; j < 4; ++j)
                acc[i][j] = __builtin_amdgcn_mfma_f32_16x16x32_bf16(afr[i], bfr[j], acc[i][j], 0, 0, 0);
    }
    asm volatile("s_waitcnt vmcnt(0)" ::: "memory");   // drain tail prefetches before LDS dies
}

// ---------------- merged q-GEMM (256 blocks) + kv-GEMM (32 blocks) ----------------
__global__ void __launch_bounds__(256)
gemm_qkv_kernel(const u16* __restrict__ xb, const u16* __restrict__ wqt, u16* __restrict__ qb,
                const u16* __restrict__ csb, const u16* __restrict__ wkvt,
                u16* __restrict__ kb, u16* __restrict__ vt)
{
    constexpr int STAGE = 8192;
    __shared__ u16 lds[4 * STAGE];   // 64 KB
    const int bid = blockIdx.x;
    const int tid = threadIdx.x;
    const int wave = tid >> 6, lane = tid & 63;
    const int wm = (wave & 1) * 64, wn = (wave >> 1) * 64;
    const int ml = lane & 15, quad = lane >> 4;
    const bool isQ = bid < 256;
    const u16 *A, *Bt;
    int m0, n0;
    if (isQ) { m0 = (bid & 15) * 128; n0 = (bid >> 4) * 128; A = xb + (size_t)m0 * GK; Bt = wqt + (size_t)n0 * GK; }
    else     { int b2 = bid - 256; m0 = (b2 & 3) * 128; n0 = (b2 >> 2) * 128; A = csb + (size_t)m0 * GK; Bt = wkvt + (size_t)n0 * GK; }

    f32x4 acc[4][4];
    gemm_core(A, Bt, lds, acc);

#pragma unroll
    for (int i = 0; i < 4; ++i)
#pragma unroll
        for (int j = 0; j < 4; ++j)
#pragma unroll
            for (int rr = 0; rr < 4; ++rr) {
                int gr = m0 + wm + i * 16 + quad * 4 + rr;
                int gc = n0 + wn + j * 16 + ml;
                float val = acc[i][j][rr];
                if (isQ) {
                    qb[(size_t)gr * 2048 + gc] = f2bf(val);
                } else if (gc < 512) {
                    kb[(size_t)gr * 512 + gc] = f2bf(val);
                } else {
                    int g = (gc - 512) >> 7, d = (gc - 512) & 127;
                    int bn = gr >> 5, lat = gr & 31;
                    vt[(((size_t)bn * 4 + g) << 12) + (d << 5) + lat] = f2bf(val);
                }
            }
}

// ---------------- out = (y @ Wo) * tanh(gate) ----------------
__global__ void __launch_bounds__(256)
gemm_out_kernel(const u16* __restrict__ yb, const u16* __restrict__ wot,
                float* __restrict__ out, const float* __restrict__ gate)
{
    constexpr int STAGE = 8192;
    __shared__ u16 lds[4 * STAGE];   // 64 KB
    const int tid = threadIdx.x;
    const int wave = tid >> 6, lane = tid & 63;
    const int wm = (wave & 1) * 64, wn = (wave >> 1) * 64;
    const int ml = lane & 15, quad = lane >> 4;
    const int m0 = blockIdx.x * 128, n0 = blockIdx.y * 128;

    f32x4 acc[4][4];
    gemm_core(yb + (size_t)m0 * GK, wot + (size_t)n0 * GK, lds, acc);

    const float scl = tanhf(gate[0]);
#pragma unroll
    for (int i = 0; i < 4; ++i)
#pragma unroll
        for (int j = 0; j < 4; ++j)
#pragma unroll
            for (int rr = 0; rr < 4; ++rr) {
                int gr = m0 + wm + i * 16 + quad * 4 + rr;
                int gc = n0 + wn + j * 16 + ml;
                out[(size_t)gr * 2048 + gc] = acc[i][j][rr] * scl;
            }
}

// ---------------- MFMA attention (verified): 8 tokens x 1 group per wave ----------------
#define KSTR 136
#define VSTR 40
__global__ void __launch_bounds__(64)
attn_mfma_kernel(const u16* __restrict__ qb, const u16* __restrict__ kb,
                 const u16* __restrict__ vt, const int* __restrict__ sorted,
                 const int4* __restrict__ tiles, const int* __restrict__ ntiles,
                 u16* __restrict__ yb)
{
    const int tile = blockIdx.x;
    if (tile >= *ntiles) return;
    const int g = blockIdx.y;
    const int4 td = tiles[tile];
    const int bucket = td.x, start = td.y, cnt = td.z;
    const int lane = threadIdx.x;
    const int ml = lane & 15, quad = lane >> 4;

    __shared__ u16 k_lds[32 * KSTR];
    __shared__ u16 v_lds[128 * VSTR];
    __shared__ u16 p_lds[32 * VSTR];
    __shared__ int tok_s[TTILE];

    if (lane < TTILE) tok_s[lane] = (lane < cnt) ? sorted[start + lane] : -1;

    {
        const u16* ksrc = kb + (size_t)bucket * 32 * 512 + g * 128;
        const u16* vsrc = vt + ((size_t)bucket * 4 + g) * 4096;
#pragma unroll
        for (int rr = 0; rr < 8; ++rr) {
            int f = rr * 64 + lane;
            int krow = f >> 4, kc = (f & 15) * 8;
            *(u16x8*)&k_lds[krow * KSTR + kc] = *(const u16x8*)(ksrc + (size_t)krow * 512 + kc);
            int vd = f >> 2, vc = (f & 3) * 8;
            *(u16x8*)&v_lds[vd * VSTR + vc] = *(const u16x8*)(vsrc + (size_t)f * 8);
        }
    }
    __syncthreads();

    f32x4 sc[2][2];
#pragma unroll
    for (int i = 0; i < 2; ++i)
#pragma unroll
        for (int j = 0; j < 2; ++j) sc[i][j] = (f32x4){0.f, 0.f, 0.f, 0.f};
    const int tokA = tok_s[ml & 7];
    const u16* qrow = qb + (size_t)(tokA >= 0 ? tokA : 0) * 2048 + g * 512 + (ml >> 3) * 128;
#pragma unroll
    for (int s = 0; s < 4; ++s) {
        bf16x8 bfr0 = *(const bf16x8*)&k_lds[ml * KSTR + s * 32 + quad * 8];
        bf16x8 bfr1 = *(const bf16x8*)&k_lds[(16 + ml) * KSTR + s * 32 + quad * 8];
#pragma unroll
        for (int i = 0; i < 2; ++i) {
            bf16x8 afr = *(const bf16x8*)(qrow + i * 256 + s * 32 + quad * 8);
            sc[i][0] = __builtin_amdgcn_mfma_f32_16x16x32_bf16(afr, bfr0, sc[i][0], 0, 0, 0);
            sc[i][1] = __builtin_amdgcn_mfma_f32_16x16x32_bf16(afr, bfr1, sc[i][1], 0, 0, 0);
        }
    }

    const float scale = 0.088388347648318447f;   // 1/sqrt(128)
#pragma unroll
    for (int i = 0; i < 2; ++i)
#pragma unroll
        for (int reg = 0; reg < 4; ++reg) {
            float s0 = sc[i][0][reg] * scale;
            float s1 = sc[i][1][reg] * scale;
            float mx = fmaxf(s0, s1);
            mx = fmaxf(mx, __shfl_xor(mx, 1));
            mx = fmaxf(mx, __shfl_xor(mx, 2));
            mx = fmaxf(mx, __shfl_xor(mx, 4));
            mx = fmaxf(mx, __shfl_xor(mx, 8));
            float e0 = __expf(s0 - mx), e1 = __expf(s1 - mx);
            float sm = e0 + e1;
            sm += __shfl_xor(sm, 1);
            sm += __shfl_xor(sm, 2);
            sm += __shfl_xor(sm, 4);
            sm += __shfl_xor(sm, 8);
            float inv = 1.0f / sm;
            int prow = i * 16 + quad * 4 + reg;
            p_lds[prow * VSTR + ml]      = f2bf(e0 * inv);
            p_lds[prow * VSTR + 16 + ml] = f2bf(e1 * inv);
        }
    __syncthreads();

    bf16x8 pfr[2], vfr[8];
    pfr[0] = *(const bf16x8*)&p_lds[ml * VSTR + quad * 8];
    pfr[1] = *(const bf16x8*)&p_lds[(16 + ml) * VSTR + quad * 8];
#pragma unroll
    for (int j = 0; j < 8; ++j)
        vfr[j] = *(const bf16x8*)&v_lds[(j * 16 + ml) * VSTR + quad * 8];
#pragma unroll
    for (int i = 0; i < 2; ++i)
#pragma unroll
        for (int j = 0; j < 8; ++j) {
            f32x4 o = (f32x4){0.f, 0.f, 0.f, 0.f};
            o = __builtin_amdgcn_mfma_f32_16x16x32_bf16(pfr[i], vfr[j], o, 0, 0, 0);
#pragma unroll
            for (int reg = 0; reg < 4; ++reg) {
                int m = quad * 4 + reg;
                int tok = tok_s[m & 7];
                if (tok >= 0) {
                    int r = i * 2 + (m >> 3);
                    yb[(size_t)tok * 2048 + g * 512 + r * 128 + j * 16 + ml] = f2bf(o[reg]);
                }
            }
        }
}

extern "C" void kernel_launch(void* const* d_in, const int* in_sizes, int n_in,
                              void* d_out, int out_size, void* d_ws, size_t ws_size,
                              hipStream_t stream) {
    const float* x    = (const float*)d_in[0];
    const float* cs   = (const float*)d_in[1];
    const int*   cm   = (const int*)d_in[2];
    const float* Wq   = (const float*)d_in[3];
    const float* Wk   = (const float*)d_in[4];
    const float* Wv   = (const float*)d_in[5];
    const float* Wo   = (const float*)d_in[6];
    const float* gate = (const float*)d_in[7];
    float* out = (float*)d_out;

    // workspace layout (16B aligned). Every GEMM A/Bt panel is followed by
    // >=192 B of mapped workspace (pipelined prefetch overreads <=192 B).
    char* w = (char*)d_ws;
    u16* xb   = (u16*)w;  w += (size_t)MROWS * CC * 2;        // 8.4 MB
    u16* wqt  = (u16*)w;  w += (size_t)CC * CC * 2;           // 8.4 MB
    u16* wot  = (u16*)w;  w += (size_t)CC * CC * 2;           // 8.4 MB
    u16* qb   = (u16*)w;  w += (size_t)MROWS * CC * 2;        // 8.4 MB
    u16* yb   = (u16*)w;  w += (size_t)MROWS * CC * 2;        // 8.4 MB
    u16* csb  = (u16*)w;  w += (size_t)CSROWS * CC * 2;       // 2.1 MB
    u16* wkvt = (u16*)w;  w += (size_t)1024 * CC * 2;         // 4.2 MB
    u16* kb   = (u16*)w;  w += (size_t)CSROWS * 512 * 2;      // 0.5 MB
    u16* vt   = (u16*)w;  w += (size_t)64 * 128 * 32 * 2;     // 0.5 MB
    int* sorted = (int*)w; w += (size_t)MROWS * 4;
    int4* tiles = (int4*)w; w += (size_t)MAXTILES * 16;
    int* ntiles = (int*)w;  w += 4096;                        // + overread pad

    // 1) all preprocessing in one launch
    prep_kernel<<<PB_END, 256, 0, stream>>>(x, cs, cm, Wq, Wk, Wv, Wo,
                                            xb, csb, wqt, wkvt, wot,
                                            sorted, tiles, ntiles);
    // 2) q-GEMM + kv-GEMM merged (kv epilogue writes kb/vt directly)
    gemm_qkv_kernel<<<288, 256, 0, stream>>>(xb, wqt, qb, csb, wkvt, kb, vt);
    // 3) attention
    attn_mfma_kernel<<<dim3(MAXTILES, 4), 64, 0, stream>>>(qb, kb, vt, sorted, tiles, ntiles, yb);
    // 4) out = (y @ Wo) * tanh(gate)
    gemm_out_kernel<<<dim3(16, 16), 256, 0, stream>>>(yb, wot, out, gate);
}